// Round 11
// baseline (149.327 us; speedup 1.0000x reference)
//
#include <hip/hip_runtime.h>
#include <math.h>

#define POOL 7
#define FH 50
#define FW 50
#define FC 1024
#define NCELLS (FH * FW)      // 2500
#define CH_PER_BLOCK 8        // channels staged per block (32B/cell in LDS)
#define CHG4 2                // vf4-groups per cell per block
#define LDS_STRIDE 3          // padded cell stride in vf4 (48B) — kills
                              // pow2 bank aliasing; slot 2 is never read
#define CH_GROUPS (FC / CH_PER_BLOCK)    // 128 channel groups
#define NSPLIT 2              // bin-range splits -> 256 blocks = 1/CU
#define THREADS 512           // 8 waves

typedef float vf4 __attribute__((ext_vector_type(4)));

static __device__ __forceinline__ vf4 vmax4(vf4 a, vf4 b) {
    vf4 r;
    r.x = fmaxf(a.x, b.x);
    r.y = fmaxf(a.y, b.y);
    r.z = fmaxf(a.z, b.z);
    r.w = fmaxf(a.w, b.w);
    return r;
}

// CHANNEL-MAJOR LDS RoI max-pool (hardened rev of R10, which never ran:
// container failed twice — possibly its 160,000B static LDS at the 160KiB
// edge; this rev stays inside the HW-verified 128 KiB envelope).
//
// Theory unchanged: nine rounds of global-path variation (MLP 2->8-deep
// asm-forced, occupancy 5->16 waves/CU, layouts, persistent waves, 2x
// volume cut) all landed at ~44+-3 us — scattered-granule L2 read serves
// ~10 TB/s aggregate regardless of issue pattern. The 433 MB read is pure
// cross-ROI re-read of a 10.2 MB map; move that reuse into LDS (69 TB/s
// aggregate).
//
// Block = (8-channel group, bin-range half). Stage the 8-channel slice of
// the WHOLE 50x50 map into LDS (2500 cells x 32B, padded stride 48B =
// 120,000 B), then compute every (bin, ch4) output in range from LDS only.
// Global reads collapse to staging (256 blocks x 80KB = 20 MB, LLC-served).
// Padded stride: cell start bank = (12*cell)%32 — 8 distinct positions, no
// pow2 aliasing (G4). Lane pairs (g=0,1) of one bin write 32B contiguous.
//
// Bin bounds use the FULL reference logic per (thread, bin) — bit-exact,
// no fast-path specialization risk.
__global__ __launch_bounds__(THREADS, 1) void roipool_lds_kernel(
    const float* __restrict__ fm,     // [FH, FW, FC]
    const float* __restrict__ rois,   // [N, 4] (y1, x1, y2, x2) normalized
    float* __restrict__ out,          // [N, 7, 7, FC]
    int nrois)
{
    __shared__ vf4 lds4[NCELLS * LDS_STRIDE];    // 7500 vf4 = 120,000 B

    const int b     = blockIdx.x;
    const int chgrp = b & (CH_GROUPS - 1);   // fast index -> XCD spread
    const int split = b >> 7;                // 2 bin-range halves
    const int c0ch  = chgrp * CH_PER_BLOCK;  // channel base of this block

    // ---- stage the 8-channel slice of the whole map into LDS ----
    for (int m = threadIdx.x; m < NCELLS * CHG4; m += THREADS) {
        const int cell = m >> 1;
        const int g    = m & 1;
        const vf4 v = *reinterpret_cast<const vf4*>(
            fm + (size_t)cell * FC + c0ch + g * 4);
        lds4[cell * LDS_STRIDE + g] = v;
    }
    __syncthreads();

    // ---- bin range of this split ----
    const int btot = nrois * POOL * POOL;
    const int per  = (btot + NSPLIT - 1) / NSPLIT;
    const int bq0  = split * per;
    const int bq1  = (bq0 + per < btot) ? (bq0 + per) : btot;
    const int nout = (bq1 - bq0) * CHG4;

    for (int k = threadIdx.x; k < nout; k += THREADS) {
        const int bl  = k >> 1;              // bin within range
        const int g   = k & 1;               // vf4-group within 8 channels
        const int bin = bq0 + bl;            // global bin = n*49 + i*7 + j
        const int n   = bin / 49;            // const divisor -> magic mul
        const int ij  = bin - n * 49;
        const int i   = ij / 7;
        const int j   = ij - i * 7;

        // ROI decode: truncating float->int cast, matching jnp astype(int32)
        const float4 roi = reinterpret_cast<const float4*>(rois)[n];
        const int h0 = (int)((float)FH * roi.x);
        const int w0 = (int)((float)FW * roi.y);
        const int h1 = (int)((float)FH * roi.z);
        const int w1 = (int)((float)FW * roi.w);
        const int rh = h1 - h0;
        const int rw = w1 - w0;
        const int hstep = rh / POOL;
        const int wstep = rw / POOL;

        // full reference bin bounds + empty-bin adjustment
        int sh = i * hstep;
        int eh = (i < POOL - 1) ? (i + 1) * hstep : rh;
        if (sh == eh) { if (eh < rh) eh += 1; else sh -= 1; }
        int sw = j * wstep;
        int ew = (j < POOL - 1) ? (j + 1) * wstep : rw;
        if (sw == ew) { if (ew < rw) ew += 1; else sw -= 1; }
        const int r0 = max(0, h0 + sh);
        const int r1 = min(FH, h0 + eh);
        const int cA = max(0, w0 + sw);
        const int cB = min(FW, w0 + ew);

        vf4 acc = {-INFINITY, -INFINITY, -INFINITY, -INFINITY};
        for (int r = r0; r < r1; ++r) {
            const int rowc = r * FW;
            vf4 acc2 = {-INFINITY, -INFINITY, -INFINITY, -INFINITY};
            int c = cA;
            for (; c + 1 < cB; c += 2) {
                acc  = vmax4(acc,  lds4[(rowc + c)     * LDS_STRIDE + g]);
                acc2 = vmax4(acc2, lds4[(rowc + c + 1) * LDS_STRIDE + g]);
            }
            if (c < cB) {
                acc = vmax4(acc, lds4[(rowc + c) * LDS_STRIDE + g]);
            }
            acc = vmax4(acc, acc2);
        }

        // lane pair (g=0,1) of one bin writes 32B contiguous
        vf4* o = reinterpret_cast<vf4*>(out + (size_t)bin * FC + c0ch) + g;
        __builtin_nontemporal_store(acc, o);
    }
}

extern "C" void kernel_launch(void* const* d_in, const int* in_sizes, int n_in,
                              void* d_out, int out_size, void* d_ws, size_t ws_size,
                              hipStream_t stream) {
    const float* features = (const float*)d_in[0];  // [1,50,50,1024]
    const float* rois     = (const float*)d_in[1];  // [N,4]
    float* out            = (float*)d_out;          // [N,7,7,1024]
    const int N = in_sizes[1] / 4;

    dim3 grid(CH_GROUPS * NSPLIT);                  // 256 blocks = 1/CU
    dim3 block(THREADS);
    roipool_lds_kernel<<<grid, block, 0, stream>>>(features, rois, out, N);
}

// Round 12
// 96.929 us; speedup vs baseline: 1.5406x; 1.5406x over previous
//
#include <hip/hip_runtime.h>
#include <math.h>

#define POOL 7
#define FH 50
#define FW 50
#define FC 1024
#define FC4 (FC / 4)        // 256 vf4 per spatial cell
#define CHUNKS 4            // channel chunks; 64 vf4 (256 ch) per chunk
#define F4C 64              // vf4 per cell per chunk (one wave-wide load)
#define RS (FW * FC4)       // row stride in vf4
#define JGROUPS 4           // column-bin groups: {0,1},{2,3},{4,5},{6}
#define UNITS_PER_ROI (POOL * JGROUPS)   // 28

typedef float vf4 __attribute__((ext_vector_type(4)));

static __device__ __forceinline__ vf4 vmax4(vf4 a, vf4 b) {
    vf4 r;
    r.x = fmaxf(a.x, b.x);
    r.y = fmaxf(a.y, b.y);
    r.z = fmaxf(a.z, b.z);
    r.w = fmaxf(a.w, b.w);
    return r;
}

// Specialized inner loops for wstep = W (compile-time), valid when
// wstep >= 1: col bins j<6 have width EXACTLY W (no empty-bin adjustment,
// no clamping since ROI is inside [0,1] -> region inside the feature map).
// jg < 3: 2 rows x 2W cols of unconditional independent loads per iter,
// a0/a1 split at compile-time column W. jg == 3: last bin, runtime width
// bw in [W, W+6], fixed W+6 loads with clamped index (dup-max is free).
template<int W>
static __device__ __forceinline__ void pool_w(
    const vf4* __restrict__ base,    // fm4 + (chunk*F4C + lane)
    int r0, int nrows, int w0, int rw, int jg,
    vf4& a0, vf4& a1)
{
    if (jg < 3) {
        const int c0 = w0 + (jg * 2) * W;
        const vf4* p = base + (size_t)r0 * RS + (size_t)c0 * FC4;
        int t = 0;
        for (; t + 2 <= nrows; t += 2) {
            vf4 v0[2 * W], v1[2 * W];
#pragma unroll
            for (int k = 0; k < 2 * W; ++k) v0[k] = p[k * FC4];
#pragma unroll
            for (int k = 0; k < 2 * W; ++k) v1[k] = p[RS + k * FC4];
#pragma unroll
            for (int k = 0; k < W; ++k) a0 = vmax4(a0, vmax4(v0[k], v1[k]));
#pragma unroll
            for (int k = W; k < 2 * W; ++k) a1 = vmax4(a1, vmax4(v0[k], v1[k]));
            p += 2 * RS;
        }
        if (t < nrows) {
            vf4 v0[2 * W];
#pragma unroll
            for (int k = 0; k < 2 * W; ++k) v0[k] = p[k * FC4];
#pragma unroll
            for (int k = 0; k < W; ++k) a0 = vmax4(a0, v0[k]);
#pragma unroll
            for (int k = W; k < 2 * W; ++k) a1 = vmax4(a1, v0[k]);
        }
    } else {
        const int bw = rw - 6 * W;          // [W, W+6]
        const int c0 = w0 + 6 * W;
        const vf4* p = base + (size_t)r0 * RS + (size_t)c0 * FC4;
        for (int r = 0; r < nrows; ++r) {
            vf4 v[W + 6];
#pragma unroll
            for (int k = 0; k < W + 6; ++k) {
                const int kc = (k < bw) ? k : (bw - 1);   // clamp: dup-max ok
                v[k] = p[kc * FC4];
            }
#pragma unroll
            for (int k = 0; k < W + 6; ++k) a0 = vmax4(a0, v[k]);
            p += RS;
        }
    }
}

// R5 kernel VERBATIM except one change: PLAIN stores instead of
// __builtin_nontemporal_store.
//
// Why: auditing rounds 0-11, the store path is the ONLY component never
// varied — every variant wrote 58.8 MB via nt stores in bin-scattered 1KB
// granules, at 58.8MB/44.8us = 5.1 B/cy/CU. fillBufferAligned (plain
// streaming stores) sustains 23.9 B/cy/CU on the same chip. If nt-store
// throughput caps near ~5 B/cy/CU, the 44 us invariant is the WRITE floor,
// and every null (read-volume cut R9, read-MLP R8, occupancy R6, layout
// R4) is explained: none touched the writes. This round: single variable,
// nt -> plain (write-back through L2).
//
// Everything else: R5/R2's proven structure — 8400 blocks, wave = (roi,
// row-bin, col-bin-pair, chunk); chunk = b&3 pinned per XCD (b%8
// round-robin) keeps each 2.56 MB fm slice L2-resident (FETCH 8.4 MB
// confirmed); specialized branch-free bodies (verified R5-R8).
__global__ __launch_bounds__(256) void roipool_kernel(
    const float* __restrict__ fm,     // [FH, FW, FC]
    const float* __restrict__ rois,   // [N, 4] (y1, x1, y2, x2) normalized
    float* __restrict__ out,          // [N, 7, 7, FC]
    int nunits)                       // N * POOL * JGROUPS units
{
    const int b     = blockIdx.x;
    const int chunk = b & (CHUNKS - 1);       // pinned per XCD
    const int wave  = threadIdx.x >> 6;
    const int lane  = threadIdx.x & 63;
    const int u     = (b >> 2) * 4 + wave;    // ((n*7 + i)*4 + jg)
    if (u >= nunits) return;

    const int n   = u / UNITS_PER_ROI;
    const int rem = u - n * UNITS_PER_ROI;
    const int i   = rem >> 2;
    const int jg  = rem & 3;
    const int j0  = jg * 2;
    const int jcnt = (jg < JGROUPS - 1) ? 2 : 1;

    // ROI corners: truncating float->int cast, matching jnp astype(int32)
    const float4 roi = reinterpret_cast<const float4*>(rois)[n];
    const int h0 = (int)((float)FH * roi.x);
    const int w0 = (int)((float)FW * roi.y);
    const int h1 = (int)((float)FH * roi.z);
    const int w1 = (int)((float)FW * roi.w);
    const int rh = h1 - h0;
    const int rw = w1 - w0;
    const int hstep = rh / POOL;
    const int wstep = rw / POOL;

    const int f4 = chunk * F4C + lane;        // [0, 256)
    const vf4* base = reinterpret_cast<const vf4*>(fm) + f4;

    vf4 a0 = {-INFINITY, -INFINITY, -INFINITY, -INFINITY};
    vf4 a1 = a0;

    if (hstep >= 1 && wstep >= 1 && wstep <= 3) {
        // ---- specialized fast paths (always taken for this input dist) ----
        const int r0    = h0 + i * hstep;
        const int nrows = (i < POOL - 1) ? hstep : (rh - 6 * hstep);
        switch (wstep) {
            case 1: pool_w<1>(base, r0, nrows, w0, rw, jg, a0, a1); break;
            case 2: pool_w<2>(base, r0, nrows, w0, rw, jg, a0, a1); break;
            default: pool_w<3>(base, r0, nrows, w0, rw, jg, a0, a1); break;
        }
    } else {
        // ---- generic fallback (degenerate ROIs): round-2 code ----
        int sh = i * hstep;
        int eh = (i < POOL - 1) ? (i + 1) * hstep : rh;
        if (sh == eh) { if (eh < rh) eh += 1; else sh -= 1; }
        const int r0 = max(0, h0 + sh);
        const int r1 = min(FH, h0 + eh);

        int c0[2], c1[2];
#pragma unroll
        for (int t = 0; t < 2; ++t) {
            const int j = j0 + t;
            if (j < POOL) {
                int sw = j * wstep;
                int ew = (j < POOL - 1) ? (j + 1) * wstep : rw;
                if (sw == ew) { if (ew < rw) ew += 1; else sw -= 1; }
                c0[t] = max(0, w0 + sw);
                c1[t] = min(FW, w0 + ew);
            } else {
                c0[t] = 0; c1[t] = 0;
            }
        }
        for (int r = r0; r < r1; ++r) {
            const vf4* rowp = base + (size_t)r * RS;
#pragma unroll
            for (int t = 0; t < 2; ++t) {
                vf4 acc = (t == 0) ? a0 : a1;
                for (int c = c0[t]; c < c1[t]; ++c) {
                    acc = vmax4(acc, rowp[c * FC4]);
                }
                if (t == 0) a0 = acc; else a1 = acc;
            }
        }
    }

    // PLAIN stores (the single change vs R5): write-back through L2.
    vf4* o = reinterpret_cast<vf4*>(out) + (size_t)(n * 49 + i * 7 + j0) * FC4 + f4;
    o[0] = a0;
    if (jcnt == 2) {
        o[FC4] = a1;
    }
}

extern "C" void kernel_launch(void* const* d_in, const int* in_sizes, int n_in,
                              void* d_out, int out_size, void* d_ws, size_t ws_size,
                              hipStream_t stream) {
    const float* features = (const float*)d_in[0];  // [1,50,50,1024]
    const float* rois     = (const float*)d_in[1];  // [N,4]
    float* out            = (float*)d_out;          // [N,7,7,1024]
    const int N = in_sizes[1] / 4;

    const int nunits = N * UNITS_PER_ROI;           // 8400 units
    dim3 grid(((nunits + 3) / 4) * CHUNKS);         // 8400 blocks
    dim3 block(256);
    roipool_kernel<<<grid, block, 0, stream>>>(features, rois, out, nunits);
}